// Round 6
// baseline (20186.099 us; speedup 1.0000x reference)
//
#include <hip/hip_runtime.h>

#define W 512
#define NPX (512*512)
#define NCH 48
#define NBATCH 16

// reflect-101 index mapping into [0,511]; valid for i in [-511, 1022]
__device__ __forceinline__ int refl(int i) {
    int a = i < 0 ? -i : i;
    int b = 1022 - a;
    return a < b ? a : b;
}
__device__ __forceinline__ unsigned encf(float f) {
    unsigned u = __float_as_uint(f);
    return (u & 0x80000000u) ? ~u : (u | 0x80000000u);
}
__device__ __forceinline__ float decf(unsigned e) {
    unsigned u = (e & 0x80000000u) ? (e & 0x7FFFFFFFu) : ~e;
    return __uint_as_float(u);
}
__device__ __forceinline__ unsigned long long enc64(double d) {
    unsigned long long u = (unsigned long long)__double_as_longlong(d);
    return (u & 0x8000000000000000ULL) ? ~u : (u | 0x8000000000000000ULL);
}
__device__ __forceinline__ double dec64(unsigned long long e) {
    unsigned long long u = (e & 0x8000000000000000ULL) ? (e & 0x7FFFFFFFFFFFFFFFULL) : ~e;
    return __longlong_as_double((long long)u);
}

__global__ void initK(unsigned* minenc, unsigned* maxenc, unsigned long long* rmaxenc,
                      unsigned* rowact, unsigned* colBits) {
    int t = threadIdx.x;
    if (t < NCH) { minenc[t] = 0xFFFFFFFFu; maxenc[t] = 0u; rmaxenc[t] = 0ULL; }
    for (int i = t; i < NCH*16; i += 1024) { rowact[i] = 0u; colBits[i] = 0u; }
}

// weights: gw[o*288 + k] = g[k] for k in [0, 2r], zero elsewhere (k < 288)
__global__ void gaussK(float* gw) {
    int o = blockIdx.x;
    const int rr[6] = {4, 8, 17, 34, 67, 134};
    int r = rr[o];
    float sigma = 1.4f * (float)(1 << o);
    int t = threadIdx.x;   // 512
    int n = 2*r + 1;
    float wv = 0.f;
    if (t < n) { float ft = (float)(t - r) / sigma; wv = expf(-0.5f * ft * ft); }
    __shared__ float red[512];
    red[t] = wv; __syncthreads();
    for (int s = 256; s > 0; s >>= 1) { if (t < s) red[t] += red[t + s]; __syncthreads(); }
    float sum = red[0];
    float* g = gw + o*288;
    if (t < 288) g[t] = (t < n) ? wv / sum : 0.f;
}

__global__ void minmaxK(const float4* __restrict__ x4, unsigned* minenc, unsigned* maxenc) {
    int ch = blockIdx.y, chunk = blockIdx.x, t = threadIdx.x;
    size_t base = (size_t)ch*(NPX/4) + (size_t)chunk*8192;
    float mn = 3.4e38f, mx = -3.4e38f;
    for (int i = t; i < 8192; i += 256) {
        float4 v = x4[base + i];
        mn = fminf(mn, fminf(fminf(v.x, v.y), fminf(v.z, v.w)));
        mx = fmaxf(mx, fmaxf(fmaxf(v.x, v.y), fmaxf(v.z, v.w)));
    }
    for (int o = 32; o; o >>= 1) { mn = fminf(mn, __shfl_down(mn, o)); mx = fmaxf(mx, __shfl_down(mx, o)); }
    __shared__ float smn[4], smx[4];
    if ((t & 63) == 0) { smn[t >> 6] = mn; smx[t >> 6] = mx; }
    __syncthreads();
    if (t == 0) {
        for (int i = 1; i < 4; i++) { mn = fminf(mn, smn[i]); mx = fmaxf(mx, smx[i]); }
        atomicMin(&minenc[ch], encf(mn));
        atomicMax(&maxenc[ch], encf(mx));
    }
}

__global__ void scaleK(const unsigned* minenc, const unsigned* maxenc, double* gsd) {
    int t = threadIdx.x;
    if (t >= NCH) return;
    double mn = (double)decf(minenc[t]), mx = (double)decf(maxenc[t]);
    gsd[t] = 255.0 / (mx - mn + 1e-12);
}

// Harris R (fp64 direct) + Laplacian base. 32x32 tile/block, 5.2KB LDS.
__global__ __launch_bounds__(256) void lapRK(const float* __restrict__ x, const double* __restrict__ gsd,
                      float* __restrict__ lap, double* __restrict__ Rb,
                      unsigned long long* __restrict__ rmaxenc) {
    __shared__ float in[36*36];
    int ch = blockIdx.z;
    int px0 = blockIdx.x * 32, py0 = blockIdx.y * 32;
    const float* s = x + (size_t)ch*NPX;
    int t = threadIdx.x;
    for (int i = t; i < 36*36; i += 256) {
        int yy = i / 36, xx = i - yy*36;
        in[i] = s[(size_t)refl(py0 - 2 + yy)*W + refl(px0 - 2 + xx)];
    }
    __syncthreads();
    double sd = gsd[ch], s2 = sd*sd;
    int tx = t & 31, ty0 = (t >> 5) * 4;
    int gx = px0 + tx;
    int cb = gx ? tx : 1;               // local col of window base
    double m = -1e308;
    #pragma unroll
    for (int q = 0; q < 4; q++) {
        int ly = ty0 + q;
        int gy = py0 + ly;
        int rb = gy ? ly : 1;           // local row of window base
        double w[4][4];
        #pragma unroll
        for (int j = 0; j < 4; j++) {
            const float* rp = &in[(rb + j)*36 + cb];
            w[j][0] = (double)rp[0]; w[j][1] = (double)rp[1];
            w[j][2] = (double)rp[2]; w[j][3] = (double)rp[3];
        }
        double cs1[4], cs2[4], rs[4][2];
        #pragma unroll
        for (int c2 = 0; c2 < 4; c2++) {
            cs1[c2] = w[0][c2] + 2.0*w[1][c2] + w[2][c2];
            cs2[c2] = w[1][c2] + 2.0*w[2][c2] + w[3][c2];
        }
        #pragma unroll
        for (int j = 0; j < 4; j++) {
            rs[j][0] = w[j][0] + 2.0*w[j][1] + w[j][2];
            rs[j][1] = w[j][1] + 2.0*w[j][2] + w[j][3];
        }
        double Sxx = 0, Syy = 0, Sxy = 0;
        {
            double ix, iy;
            ix = cs1[2]-cs1[0]; iy = rs[2][0]-rs[0][0]; Sxx += ix*ix; Syy += iy*iy; Sxy += ix*iy;
            ix = cs1[3]-cs1[1]; iy = rs[2][1]-rs[0][1]; Sxx += ix*ix; Syy += iy*iy; Sxy += ix*iy;
            ix = cs2[2]-cs2[0]; iy = rs[3][0]-rs[1][0]; Sxx += ix*ix; Syy += iy*iy; Sxy += ix*iy;
            ix = cs2[3]-cs2[1]; iy = rs[3][1]-rs[1][1]; Sxx += ix*ix; Syy += iy*iy; Sxy += ix*iy;
        }
        Sxx *= s2; Syy *= s2; Sxy *= s2;
        double tr = Sxx + Syy;
        double R = Sxx*Syy - Sxy*Sxy - 0.04*tr*tr;
        Rb[(size_t)ch*NPX + (size_t)gy*W + gx] = R;
        const float* c = &in[(ly+2)*36 + (tx+2)];
        double l = 2.0*((double)c[-37] + (double)c[-35] + (double)c[35] + (double)c[37]) - 8.0*(double)c[0];
        lap[(size_t)ch*NPX + (size_t)gy*W + gx] = (float)(sd * l);
        m = fmax(m, R);
    }
    for (int o = 32; o; o >>= 1) m = fmax(m, __shfl_down(m, o));
    __shared__ double sred[4];
    if ((t & 63) == 0) sred[t >> 6] = m;
    __syncthreads();
    if (t == 0) {
        for (int i = 1; i < 4; i++) m = fmax(m, sred[i]);
        atomicMax(&rmaxenc[ch], enc64(m));
    }
}

// fused threshold + 3x3 dilate; builds row-activity and column-activity bitmaps
__global__ __launch_bounds__(256) void maskTK(const double* __restrict__ Rb,
                                              const unsigned long long* __restrict__ rmaxenc,
                                              unsigned char* __restrict__ maskb,
                                              unsigned* __restrict__ rowact,
                                              unsigned* __restrict__ colBits) {
    __shared__ int bt[34*34];
    __shared__ unsigned rw, cw;
    int ch = blockIdx.z;
    int px0 = blockIdx.x*32, py0 = blockIdx.y*32;
    double thr = 0.01 * dec64(rmaxenc[ch]);
    const double* R = Rb + (size_t)ch*NPX;
    int t = threadIdx.x;
    if (t == 0) { rw = 0u; cw = 0u; }
    for (int i = t; i < 34*34; i += 256) {
        int yy = i / 34, xx = i - yy*34;
        int gy = py0 - 1 + yy, gx = px0 - 1 + xx;
        int v = 0;
        if ((unsigned)gy < 512u && (unsigned)gx < 512u) v = (R[(size_t)gy*W + gx] > thr) ? 1 : 0;
        bt[i] = v;
    }
    __syncthreads();
    int tx = t & 31, ty0 = (t >> 5) * 4;
    int colv = 0;
    #pragma unroll
    for (int q = 0; q < 4; q++) {
        int ly = ty0 + q;
        int c = (ly+1)*34 + tx + 1;
        int v = bt[c-35] | bt[c-34] | bt[c-33] | bt[c-1] | bt[c] | bt[c+1] | bt[c+33] | bt[c+34] | bt[c+35];
        maskb[(size_t)ch*NPX + (size_t)(py0+ly)*W + px0 + tx] = (unsigned char)v;
        colv |= v;
        unsigned long long bal = __ballot(v != 0);
        int lane = t & 63;
        if (lane == 0 && (unsigned)bal) atomicOr(&rw, 1u << (ty0 + q));
        if (lane == 32 && (unsigned)(bal >> 32)) atomicOr(&rw, 1u << (ty0 + q));
    }
    if (colv) atomicOr(&cw, 1u << tx);
    __syncthreads();
    if (t == 0) {
        if (rw) atomicOr(&rowact[ch*16 + (py0 >> 5)], rw);
        if (cw) atomicOr(&colBits[ch*16 + blockIdx.x], cw);
    }
}

// compact the per-channel column bitmap into a sorted list
__global__ void colListK(const unsigned* __restrict__ colBits,
                         unsigned short* __restrict__ colList, int* __restrict__ ncols) {
    int ch = blockIdx.x;
    int lane = threadIdx.x;   // 64
    unsigned word = (lane < 16) ? colBits[ch*16 + lane] : 0u;
    int cnt = __popc(word);
    int pre = cnt;
    for (int o = 1; o < 64; o <<= 1) { int v2 = __shfl_up(pre, o); if (lane >= o) pre += v2; }
    int base = pre - cnt;
    if (lane == 63) ncols[ch] = pre;
    while (word) {
        int b = __ffs((int)word) - 1;
        colList[ch*512 + base++] = (unsigned short)(lane*32 + b);
        word &= word - 1;
    }
}

// sparse horizontal blur: 8 rows/block; compute only masked columns (colList).
// Lane l takes list entries l, l+32, ... ; exact 2r+1 taps, ascending (FP-identical).
__global__ __launch_bounds__(256) void rowblurS(const float* __restrict__ src, float* __restrict__ dst,
                                                const float* __restrict__ gwo, int r,
                                                const unsigned* __restrict__ rowact,
                                                const unsigned short* __restrict__ colList,
                                                const int* __restrict__ ncols) {
    int ch = blockIdx.y;
    int row0 = blockIdx.x * 8;
    int t = threadIdx.x;
    // early exit: no masked row in [row0-r, row0+7+r]
    {
        int lo = row0 - r; if (lo < 0) lo = 0;
        int hi = row0 + 7 + r; if (hi > 511) hi = 511;
        int w0 = lo >> 5, w1 = hi >> 5;
        int lane = t & 63;
        unsigned any = 0;
        if (lane <= w1 - w0) {
            int wi = w0 + lane;
            unsigned word = rowact[ch*16 + wi];
            int b0 = wi*32;
            int lo2 = lo > b0 ? lo - b0 : 0;
            int hi2 = hi < b0 + 31 ? hi - b0 : 31;
            unsigned mlo = ~0u << lo2;
            unsigned mhi = (hi2 == 31) ? ~0u : ((1u << (hi2 + 1)) - 1u);
            any = word & mlo & mhi;
        }
        if (!__any((int)(any != 0))) return;
    }
    __shared__ float ES[8][784];
    __shared__ float wls[288];
    int lr = t >> 5, xi = t & 31;
    for (int i = t; i < 288; i += 256) wls[i] = gwo[i];
    const float* s = src + (size_t)ch*NPX + (size_t)(row0 + lr)*W;
    int n = W + 2*r;
    for (int j = xi; j < 784; j += 32)
        ES[lr][j] = (j < n) ? s[refl(j - r)] : 0.f;
    __syncthreads();
    float* drow = dst + (size_t)ch*NPX + (size_t)(row0 + lr)*W;
    int nc = ncols[ch];
    int nt = 2*r + 1;
    const unsigned short* cl = colList + ch*512;
    for (int i = xi; i < nc; i += 32) {
        int col = cl[i];
        float acc = 0.f;
        const float* e = &ES[lr][col];
        for (int k = 0; k < nt; k++) acc = fmaf(wls[k], e[k], acc);
        drow[col] = acc;
    }
}

// sparse vertical blur: scan mask bytes; per masked pixel gather 2r+1 taps from T
// (column support proven within masked cols; rows within +-r, rowblurS covers them).
// out combined via atomicMax on non-negative float bits (max is order-independent).
__global__ __launch_bounds__(256) void colblurS(const float* __restrict__ T,
                                                const unsigned char* __restrict__ maskb,
                                                float* __restrict__ out,
                                                const float* __restrict__ gwo,
                                                int r, float sigma) {
    int g = blockIdx.x*256 + threadIdx.x;
    int ch = g >> 14;                 // 16384 16-px chunks per channel
    int px0 = (g & 16383) << 4;
    const unsigned char* mp = maskb + (size_t)ch*NPX + px0;
    uint4 mb = *(const uint4*)mp;
    if (!(mb.x | mb.y | mb.z | mb.w)) return;
    const float* Tc = T + (size_t)ch*NPX;
    float* ob = out + (size_t)(ch/3)*NPX;
    unsigned wv4[4] = {mb.x, mb.y, mb.z, mb.w};
    int nt = 2*r + 1;
    #pragma unroll
    for (int wq = 0; wq < 4; wq++) {
        unsigned u = wv4[wq];
        while (u) {
            int bidx = (__ffs((int)u) - 1) >> 3;    // byte index 0..3
            u &= ~(0xFFu << (bidx*8));
            int p = px0 + wq*4 + bidx;
            int y = p >> 9, x = p & 511;
            float acc = 0.f;
            int base = y - r;
            for (int k = 0; k < nt; k++)
                acc = fmaf(gwo[k], Tc[(size_t)refl(base + k)*W + x], acc);
            float val = sigma * fabsf(acc);
            atomicMax((unsigned*)(ob + p), __float_as_uint(val));
        }
    }
}

extern "C" void kernel_launch(void* const* d_in, const int* in_sizes, int n_in,
                              void* d_out, int out_size, void* d_ws, size_t ws_size,
                              hipStream_t stream) {
    const float* x = (const float*)d_in[0];
    float* out = (float*)d_out;
    char* w = (char*)d_ws;
    unsigned* minenc           = (unsigned*)(w + 1024);
    unsigned* maxenc           = (unsigned*)(w + 1280);
    unsigned long long* rmaxenc= (unsigned long long*)(w + 1536);
    double*  gsd               = (double*)(w + 256);
    float*   gw                = (float*)(w + 2048);                 // 6*288 floats (ends 8960)
    unsigned* rowact           = (unsigned*)(w + 9216);              // 48*16 words
    unsigned* colBits          = (unsigned*)(w + 12288);             // 48*16 words
    int*     ncols             = (int*)(w + 15360);                  // 48 ints
    float*   lap               = (float*)(w + 16384);                // 50331648 B
    double*  Rb                = (double*)(w + 16384 + 50331648);    // 100663296 B
    float*   T                 = (float*)Rb;                         // first 50MB, reused after maskTK
    unsigned short* colList    = (unsigned short*)(w + 16384 + 50331648 + 50331648); // 2nd 50MB of Rb, after colListK
    unsigned char* maskb       = (unsigned char*)(w + 16384 + 50331648 + 100663296); // 12582912 B

    initK<<<1, 1024, 0, stream>>>(minenc, maxenc, rmaxenc, rowact, colBits);
    gaussK<<<6, 512, 0, stream>>>(gw);
    minmaxK<<<dim3(8, 48), 256, 0, stream>>>((const float4*)x, minenc, maxenc);
    scaleK<<<1, 64, 0, stream>>>(minenc, maxenc, gsd);
    lapRK<<<dim3(16, 16, 48), 256, 0, stream>>>(x, gsd, lap, Rb, rmaxenc);
    maskTK<<<dim3(16, 16, 48), 256, 0, stream>>>(Rb, rmaxenc, maskb, rowact, colBits);
    colListK<<<48, 64, 0, stream>>>(colBits, colList, ncols);
    hipMemsetAsync(out, 0, (size_t)out_size * 4, stream);

    const int rr[6] = {4, 8, 17, 34, 67, 134};
    for (int o = 0; o < 6; ++o) {
        int r = rr[o];
        float sigma = 1.4f * (float)(1 << o);
        rowblurS<<<dim3(64, 48), 256, 0, stream>>>(lap, T, gw + o*288, r, rowact, colList, ncols);
        colblurS<<<3072, 256, 0, stream>>>(T, maskb, out, gw + o*288, r, sigma);
    }
}

// Round 7
// 878.527 us; speedup vs baseline: 22.9772x; 22.9772x over previous
//
#include <hip/hip_runtime.h>

#define W 512
#define NPX (512*512)
#define NCH 48
#define NBATCH 16

// reflect-101 index mapping into [0,511]; valid for i in [-511, 1022]
__device__ __forceinline__ int refl(int i) {
    int a = i < 0 ? -i : i;
    int b = 1022 - a;
    return a < b ? a : b;
}
__device__ __forceinline__ unsigned encf(float f) {
    unsigned u = __float_as_uint(f);
    return (u & 0x80000000u) ? ~u : (u | 0x80000000u);
}
__device__ __forceinline__ float decf(unsigned e) {
    unsigned u = (e & 0x80000000u) ? (e & 0x7FFFFFFFu) : ~e;
    return __uint_as_float(u);
}
__device__ __forceinline__ unsigned long long enc64(double d) {
    unsigned long long u = (unsigned long long)__double_as_longlong(d);
    return (u & 0x8000000000000000ULL) ? ~u : (u | 0x8000000000000000ULL);
}
__device__ __forceinline__ double dec64(unsigned long long e) {
    unsigned long long u = (e & 0x8000000000000000ULL) ? (e & 0x7FFFFFFFFFFFFFFFULL) : ~e;
    return __longlong_as_double((long long)u);
}

__global__ void initK(unsigned* minenc, unsigned* maxenc, unsigned long long* rmaxenc,
                      unsigned* rowact, unsigned* colBits) {
    int t = threadIdx.x;
    if (t < NCH) { minenc[t] = 0xFFFFFFFFu; maxenc[t] = 0u; rmaxenc[t] = 0ULL; }
    for (int i = t; i < NCH*16; i += 1024) { rowact[i] = 0u; colBits[i] = 0u; }
}

// weights: gw[o*288 + k] = g[k] for k in [0, 2r], zero elsewhere (k < 288)
__global__ void gaussK(float* gw) {
    int o = blockIdx.x;
    const int rr[6] = {4, 8, 17, 34, 67, 134};
    int r = rr[o];
    float sigma = 1.4f * (float)(1 << o);
    int t = threadIdx.x;   // 512
    int n = 2*r + 1;
    float wv = 0.f;
    if (t < n) { float ft = (float)(t - r) / sigma; wv = expf(-0.5f * ft * ft); }
    __shared__ float red[512];
    red[t] = wv; __syncthreads();
    for (int s = 256; s > 0; s >>= 1) { if (t < s) red[t] += red[t + s]; __syncthreads(); }
    float sum = red[0];
    float* g = gw + o*288;
    if (t < 288) g[t] = (t < n) ? wv / sum : 0.f;
}

__global__ void minmaxK(const float4* __restrict__ x4, unsigned* minenc, unsigned* maxenc) {
    int ch = blockIdx.y, chunk = blockIdx.x, t = threadIdx.x;
    size_t base = (size_t)ch*(NPX/4) + (size_t)chunk*8192;
    float mn = 3.4e38f, mx = -3.4e38f;
    for (int i = t; i < 8192; i += 256) {
        float4 v = x4[base + i];
        mn = fminf(mn, fminf(fminf(v.x, v.y), fminf(v.z, v.w)));
        mx = fmaxf(mx, fmaxf(fmaxf(v.x, v.y), fmaxf(v.z, v.w)));
    }
    for (int o = 32; o; o >>= 1) { mn = fminf(mn, __shfl_down(mn, o)); mx = fmaxf(mx, __shfl_down(mx, o)); }
    __shared__ float smn[4], smx[4];
    if ((t & 63) == 0) { smn[t >> 6] = mn; smx[t >> 6] = mx; }
    __syncthreads();
    if (t == 0) {
        for (int i = 1; i < 4; i++) { mn = fminf(mn, smn[i]); mx = fmaxf(mx, smx[i]); }
        atomicMin(&minenc[ch], encf(mn));
        atomicMax(&maxenc[ch], encf(mx));
    }
}

__global__ void scaleK(const unsigned* minenc, const unsigned* maxenc, double* gsd) {
    int t = threadIdx.x;
    if (t >= NCH) return;
    double mn = (double)decf(minenc[t]), mx = (double)decf(maxenc[t]);
    gsd[t] = 255.0 / (mx - mn + 1e-12);
}

// Harris R (fp64 direct) + Laplacian base. 32x32 tile/block, 5.2KB LDS.
__global__ __launch_bounds__(256) void lapRK(const float* __restrict__ x, const double* __restrict__ gsd,
                      float* __restrict__ lap, double* __restrict__ Rb,
                      unsigned long long* __restrict__ rmaxenc) {
    __shared__ float in[36*36];
    int ch = blockIdx.z;
    int px0 = blockIdx.x * 32, py0 = blockIdx.y * 32;
    const float* s = x + (size_t)ch*NPX;
    int t = threadIdx.x;
    for (int i = t; i < 36*36; i += 256) {
        int yy = i / 36, xx = i - yy*36;
        in[i] = s[(size_t)refl(py0 - 2 + yy)*W + refl(px0 - 2 + xx)];
    }
    __syncthreads();
    double sd = gsd[ch], s2 = sd*sd;
    int tx = t & 31, ty0 = (t >> 5) * 4;
    int gx = px0 + tx;
    int cb = gx ? tx : 1;               // local col of window base
    double m = -1e308;
    #pragma unroll
    for (int q = 0; q < 4; q++) {
        int ly = ty0 + q;
        int gy = py0 + ly;
        int rb = gy ? ly : 1;           // local row of window base
        double w[4][4];
        #pragma unroll
        for (int j = 0; j < 4; j++) {
            const float* rp = &in[(rb + j)*36 + cb];
            w[j][0] = (double)rp[0]; w[j][1] = (double)rp[1];
            w[j][2] = (double)rp[2]; w[j][3] = (double)rp[3];
        }
        double cs1[4], cs2[4], rs[4][2];
        #pragma unroll
        for (int c2 = 0; c2 < 4; c2++) {
            cs1[c2] = w[0][c2] + 2.0*w[1][c2] + w[2][c2];
            cs2[c2] = w[1][c2] + 2.0*w[2][c2] + w[3][c2];
        }
        #pragma unroll
        for (int j = 0; j < 4; j++) {
            rs[j][0] = w[j][0] + 2.0*w[j][1] + w[j][2];
            rs[j][1] = w[j][1] + 2.0*w[j][2] + w[j][3];
        }
        double Sxx = 0, Syy = 0, Sxy = 0;
        {
            double ix, iy;
            ix = cs1[2]-cs1[0]; iy = rs[2][0]-rs[0][0]; Sxx += ix*ix; Syy += iy*iy; Sxy += ix*iy;
            ix = cs1[3]-cs1[1]; iy = rs[2][1]-rs[0][1]; Sxx += ix*ix; Syy += iy*iy; Sxy += ix*iy;
            ix = cs2[2]-cs2[0]; iy = rs[3][0]-rs[1][0]; Sxx += ix*ix; Syy += iy*iy; Sxy += ix*iy;
            ix = cs2[3]-cs2[1]; iy = rs[3][1]-rs[1][1]; Sxx += ix*ix; Syy += iy*iy; Sxy += ix*iy;
        }
        Sxx *= s2; Syy *= s2; Sxy *= s2;
        double tr = Sxx + Syy;
        double R = Sxx*Syy - Sxy*Sxy - 0.04*tr*tr;
        Rb[(size_t)ch*NPX + (size_t)gy*W + gx] = R;
        const float* c = &in[(ly+2)*36 + (tx+2)];
        double l = 2.0*((double)c[-37] + (double)c[-35] + (double)c[35] + (double)c[37]) - 8.0*(double)c[0];
        lap[(size_t)ch*NPX + (size_t)gy*W + gx] = (float)(sd * l);
        m = fmax(m, R);
    }
    for (int o = 32; o; o >>= 1) m = fmax(m, __shfl_down(m, o));
    __shared__ double sred[4];
    if ((t & 63) == 0) sred[t >> 6] = m;
    __syncthreads();
    if (t == 0) {
        for (int i = 1; i < 4; i++) m = fmax(m, sred[i]);
        atomicMax(&rmaxenc[ch], enc64(m));
    }
}

// fused threshold + 3x3 dilate; writes TRANSPOSED mask maskT[ch][x][y];
// also builds row-activity and column-activity bitmaps
__global__ __launch_bounds__(256) void maskTK(const double* __restrict__ Rb,
                                              const unsigned long long* __restrict__ rmaxenc,
                                              unsigned char* __restrict__ maskT,
                                              unsigned* __restrict__ rowact,
                                              unsigned* __restrict__ colBits) {
    __shared__ int bt[34*34];
    __shared__ unsigned char vt[32][33];
    __shared__ unsigned rw, cw;
    int ch = blockIdx.z;
    int px0 = blockIdx.x*32, py0 = blockIdx.y*32;
    double thr = 0.01 * dec64(rmaxenc[ch]);
    const double* R = Rb + (size_t)ch*NPX;
    int t = threadIdx.x;
    if (t == 0) { rw = 0u; cw = 0u; }
    for (int i = t; i < 34*34; i += 256) {
        int yy = i / 34, xx = i - yy*34;
        int gy = py0 - 1 + yy, gx = px0 - 1 + xx;
        int v = 0;
        if ((unsigned)gy < 512u && (unsigned)gx < 512u) v = (R[(size_t)gy*W + gx] > thr) ? 1 : 0;
        bt[i] = v;
    }
    __syncthreads();
    int tx = t & 31, ty0 = (t >> 5) * 4;
    int colv = 0;
    #pragma unroll
    for (int q = 0; q < 4; q++) {
        int ly = ty0 + q;
        int c = (ly+1)*34 + tx + 1;
        int v = bt[c-35] | bt[c-34] | bt[c-33] | bt[c-1] | bt[c] | bt[c+1] | bt[c+33] | bt[c+34] | bt[c+35];
        vt[tx][ly] = (unsigned char)v;
        colv |= v;
        unsigned long long bal = __ballot(v != 0);
        int lane = t & 63;
        if (lane == 0 && (unsigned)bal) atomicOr(&rw, 1u << (ty0 + q));
        if (lane == 32 && (unsigned)(bal >> 32)) atomicOr(&rw, 1u << (ty0 + q));
    }
    if (colv) atomicOr(&cw, 1u << tx);
    __syncthreads();
    // write transposed mask: thread t -> x row xl = t>>3, 4-byte y segment seg = t&7
    int xl = t >> 3, seg = t & 7;
    uchar4 u4 = make_uchar4(vt[xl][seg*4+0], vt[xl][seg*4+1], vt[xl][seg*4+2], vt[xl][seg*4+3]);
    *(uchar4*)(maskT + (size_t)ch*NPX + (size_t)(px0 + xl)*W + py0 + seg*4) = u4;
    if (t == 0) {
        if (rw) atomicOr(&rowact[ch*16 + (py0 >> 5)], rw);
        if (cw) atomicOr(&colBits[ch*16 + blockIdx.x], cw);
    }
}

// horizontal blur with TRANSPOSED output: 16 rows/block, 16 px/thread x 2 halves,
// 16-tap chunks (ascending taps, FP-identical). Writes Tt[ch][x][y] via LDS
// restage -> 64B/lane coalesced global stores. rowact early-exit retained.
__global__ __launch_bounds__(256) void rowblurT(const float* __restrict__ src, float* __restrict__ Tt,
                                                const float* __restrict__ gwo, int r, int nc16,
                                                const unsigned* __restrict__ rowact) {
    int ch = blockIdx.y;
    int row0 = blockIdx.x * 16;
    int t = threadIdx.x;
    // early exit: no masked row in [row0-r, row0+15+r]
    {
        int lo = row0 - r; if (lo < 0) lo = 0;
        int hi = row0 + 15 + r; if (hi > 511) hi = 511;
        int w0 = lo >> 5, w1 = hi >> 5;
        int lane = t & 63;
        unsigned any = 0;
        if (lane <= w1 - w0) {
            int wi = w0 + lane;
            unsigned word = rowact[ch*16 + wi];
            int b0 = wi*32;
            int lo2 = lo > b0 ? lo - b0 : 0;
            int hi2 = hi < b0 + 31 ? hi - b0 : 31;
            unsigned mlo = ~0u << lo2;
            unsigned mhi = (hi2 == 31) ? ~0u : ((1u << (hi2 + 1)) - 1u);
            any = word & mlo & mhi;
        }
        if (!__any((int)(any != 0))) return;
    }
    extern __shared__ float sm[];   // max(16*16*49 = 12544, 512*17 = 8704) floats
    __shared__ float wls[288];
    int lr = t >> 4, xi = t & 15;
    for (int i = t; i < 288; i += 256) wls[i] = gwo[i];
    const float* s = src + (size_t)ch*NPX + (size_t)(row0 + lr)*W;
    int n = W + 2*r;
    float* ESr = sm + lr*16*49;
    for (int j = xi; j < 784; j += 16)
        ESr[(j & 15)*49 + (j >> 4)] = (j < n) ? s[refl(j - r)] : 0.f;
    __syncthreads();
    float aa[2][16];
    #pragma unroll
    for (int h = 0; h < 2; h++) {
        float a[16];
        #pragma unroll
        for (int m = 0; m < 16; m++) a[m] = 0.f;
        for (int cc = 0; cc < nc16; ++cc) {
            float wv[16], f[31];
            #pragma unroll
            for (int i = 0; i < 16; i++) wv[i] = wls[16*cc + i];
            #pragma unroll
            for (int j = 0; j < 31; j++) f[j] = ESr[(j & 15)*49 + (16*h + xi + cc + (j >> 4))];
            #pragma unroll
            for (int m = 0; m < 16; m++) {
                #pragma unroll
                for (int i = 0; i < 16; i++) a[m] = fmaf(wv[i], f[m + i], a[m]);
            }
        }
        #pragma unroll
        for (int m = 0; m < 16; m++) aa[h][m] = a[m];
    }
    __syncthreads();   // ES dead, reuse sm as ot[512][17]
    #pragma unroll
    for (int h = 0; h < 2; h++) {
        int cb = 256*h + 16*xi;
        #pragma unroll
        for (int m = 0; m < 16; m++) sm[(cb + m)*17 + lr] = aa[h][m];
    }
    __syncthreads();
    float* dto = Tt + (size_t)ch*NPX + row0;
    for (int xx = t; xx < 512; xx += 256) {
        const float* o = sm + xx*17;
        float4* d = (float4*)(dto + (size_t)xx*W);
        d[0] = make_float4(o[0],  o[1],  o[2],  o[3]);
        d[1] = make_float4(o[4],  o[5],  o[6],  o[7]);
        d[2] = make_float4(o[8],  o[9],  o[10], o[11]);
        d[3] = make_float4(o[12], o[13], o[14], o[15]);
    }
}

// vertical blur done as HORIZONTAL blur on Tt: 8 x-rows/block, 16 y/thread,
// same chunked ascending-tap loop. Zero halo overfetch, coalesced reads.
// Per-channel skip via colBits; per-wave skip via maskT; accumulates into
// transposed outT[b][x][y] (plain RMW max; z = batch so no races).
template<int WRITE0>
__global__ __launch_bounds__(256, 4) void colblurT(const float* __restrict__ Tt,
                                                   const unsigned char* __restrict__ maskT,
                                                   float* __restrict__ outT,
                                                   const float* __restrict__ gwo,
                                                   int r, int nc16, float sigma,
                                                   const unsigned* __restrict__ colBits) {
    __shared__ float ES[8*16*49];
    __shared__ float wls[288];
    int b = blockIdx.y;
    int x0 = blockIdx.x * 8;
    int t = threadIdx.x;
    int lr = t >> 5, xi = t & 31;
    for (int i = t; i < 288; i += 256) wls[i] = gwo[i];
    float vm[16];
    #pragma unroll
    for (int m = 0; m < 16; m++) vm[m] = 0.f;
    int anyAct = 0;
    int n = W + 2*r;
    float* ESr = ES + lr*16*49;
    for (int c = 0; c < 3; ++c) {
        int ch = b*3 + c;
        unsigned cbits = (colBits[ch*16 + (x0 >> 5)] >> (x0 & 31)) & 0xFFu;
        if (!cbits) continue;          // uniform per block
        anyAct = 1;
        __syncthreads();               // protect ES from previous channel's readers
        const float* s = Tt + (size_t)ch*NPX + (size_t)(x0 + lr)*W;
        for (int j = xi; j < 784; j += 32)
            ESr[(j & 15)*49 + (j >> 4)] = (j < n) ? s[refl(j - r)] : 0.f;
        __syncthreads();
        const uchar4* mp = (const uchar4*)(maskT + (size_t)ch*NPX + (size_t)(x0 + lr)*W + 16*xi);
        uchar4 m0 = mp[0], m1 = mp[1], m2 = mp[2], m3 = mp[3];
        unsigned mk = 0;
        mk |=  (m0.x?1u:0u)|(m0.y?2u:0u)|(m0.z?4u:0u)|(m0.w?8u:0u);
        mk |= ((m1.x?1u:0u)|(m1.y?2u:0u)|(m1.z?4u:0u)|(m1.w?8u:0u)) << 4;
        mk |= ((m2.x?1u:0u)|(m2.y?2u:0u)|(m2.z?4u:0u)|(m2.w?8u:0u)) << 8;
        mk |= ((m3.x?1u:0u)|(m3.y?2u:0u)|(m3.z?4u:0u)|(m3.w?8u:0u)) << 12;
        if (__any((int)(mk != 0))) {
            float a[16];
            #pragma unroll
            for (int m = 0; m < 16; m++) a[m] = 0.f;
            for (int cc = 0; cc < nc16; ++cc) {
                float wv[16], f[31];
                #pragma unroll
                for (int i = 0; i < 16; i++) wv[i] = wls[16*cc + i];
                #pragma unroll
                for (int j = 0; j < 31; j++) f[j] = ESr[(j & 15)*49 + (xi + cc + (j >> 4))];
                #pragma unroll
                for (int m = 0; m < 16; m++) {
                    #pragma unroll
                    for (int i = 0; i < 16; i++) a[m] = fmaf(wv[i], f[m + i], a[m]);
                }
            }
            #pragma unroll
            for (int m = 0; m < 16; m++)
                if (mk & (1u << m)) vm[m] = fmaxf(vm[m], sigma * fabsf(a[m]));
        }
    }
    if (!WRITE0 && !anyAct) return;
    float* ob = outT + (size_t)b*NPX + (size_t)(x0 + lr)*W + 16*xi;
    #pragma unroll
    for (int q = 0; q < 4; q++) {
        float4 vv = make_float4(vm[4*q], vm[4*q+1], vm[4*q+2], vm[4*q+3]);
        if (!WRITE0) {
            float4 cur = ((const float4*)ob)[q];
            vv.x = fmaxf(vv.x, cur.x); vv.y = fmaxf(vv.y, cur.y);
            vv.z = fmaxf(vv.z, cur.z); vv.w = fmaxf(vv.w, cur.w);
        }
        ((float4*)ob)[q] = vv;
    }
}

// final transpose: out[b][y][x] = outT[b][x][y]
__global__ __launch_bounds__(256) void transposeK(const float* __restrict__ outT, float* __restrict__ out) {
    __shared__ float tl[32][33];
    int b = blockIdx.z;
    int x0 = blockIdx.x * 32, y0 = blockIdx.y * 32;
    int t = threadIdx.x;
    int col = t & 31, rr = t >> 5;
    const float* src = outT + (size_t)b*NPX;
    #pragma unroll
    for (int k = 0; k < 4; k++) {
        int xr = rr + 8*k;
        tl[xr][col] = src[(size_t)(x0 + xr)*W + y0 + col];
    }
    __syncthreads();
    float* d = out + (size_t)b*NPX;
    #pragma unroll
    for (int k = 0; k < 4; k++) {
        int yr = rr + 8*k;
        d[(size_t)(y0 + yr)*W + x0 + col] = tl[col][yr];
    }
}

extern "C" void kernel_launch(void* const* d_in, const int* in_sizes, int n_in,
                              void* d_out, int out_size, void* d_ws, size_t ws_size,
                              hipStream_t stream) {
    const float* x = (const float*)d_in[0];
    float* out = (float*)d_out;
    char* w = (char*)d_ws;
    unsigned* minenc           = (unsigned*)(w + 1024);
    unsigned* maxenc           = (unsigned*)(w + 1280);
    unsigned long long* rmaxenc= (unsigned long long*)(w + 1536);
    double*  gsd               = (double*)(w + 256);
    float*   gw                = (float*)(w + 2048);                 // 6*288 floats
    unsigned* rowact           = (unsigned*)(w + 9216);              // 48*16 words
    unsigned* colBits          = (unsigned*)(w + 12288);             // 48*16 words
    float*   lap               = (float*)(w + 16384);                // 50331648 B
    double*  Rb                = (double*)(w + 16384 + 50331648);    // 100663296 B (freed after maskTK)
    float*   Tt                = (float*)Rb;                         // 50331648 B  (in Rb)
    float*   outT              = (float*)(w + 16384 + 50331648 + 50331648); // 16777216 B (in Rb)
    unsigned char* maskT       = (unsigned char*)(w + 16384 + 50331648 + 100663296); // 12582912 B

    initK<<<1, 1024, 0, stream>>>(minenc, maxenc, rmaxenc, rowact, colBits);
    gaussK<<<6, 512, 0, stream>>>(gw);
    minmaxK<<<dim3(8, 48), 256, 0, stream>>>((const float4*)x, minenc, maxenc);
    scaleK<<<1, 64, 0, stream>>>(minenc, maxenc, gsd);
    lapRK<<<dim3(16, 16, 48), 256, 0, stream>>>(x, gsd, lap, Rb, rmaxenc);
    maskTK<<<dim3(16, 16, 48), 256, 0, stream>>>(Rb, rmaxenc, maskT, rowact, colBits);

    const int rr[6] = {4, 8, 17, 34, 67, 134};
    for (int o = 0; o < 6; ++o) {
        int r = rr[o];
        int nc16 = (2*r + 1 + 15) / 16;
        float sigma = 1.4f * (float)(1 << o);
        size_t lds = 16*16*49 * 4;   // 50176 B (>= 512*17*4)
        rowblurT<<<dim3(32, 48), 256, lds, stream>>>(lap, Tt, gw + o*288, r, nc16, rowact);
        if (o == 0)
            colblurT<1><<<dim3(64, 16), 256, 0, stream>>>(Tt, maskT, outT, gw + o*288, r, nc16, sigma, colBits);
        else
            colblurT<0><<<dim3(64, 16), 256, 0, stream>>>(Tt, maskT, outT, gw + o*288, r, nc16, sigma, colBits);
    }
    transposeK<<<dim3(16, 16, 16), 256, 0, stream>>>(outT, out);
}

// Round 8
// 869.415 us; speedup vs baseline: 23.2180x; 1.0105x over previous
//
#include <hip/hip_runtime.h>

#define W 512
#define NPX (512*512)
#define NCH 48
#define NBATCH 16

// reflect-101 index mapping into [0,511]; valid for i in [-511, 1022]
__device__ __forceinline__ int refl(int i) {
    int a = i < 0 ? -i : i;
    int b = 1022 - a;
    return a < b ? a : b;
}
__device__ __forceinline__ unsigned encf(float f) {
    unsigned u = __float_as_uint(f);
    return (u & 0x80000000u) ? ~u : (u | 0x80000000u);
}
__device__ __forceinline__ float decf(unsigned e) {
    unsigned u = (e & 0x80000000u) ? (e & 0x7FFFFFFFu) : ~e;
    return __uint_as_float(u);
}
__device__ __forceinline__ unsigned long long enc64(double d) {
    unsigned long long u = (unsigned long long)__double_as_longlong(d);
    return (u & 0x8000000000000000ULL) ? ~u : (u | 0x8000000000000000ULL);
}
__device__ __forceinline__ double dec64(unsigned long long e) {
    unsigned long long u = (e & 0x8000000000000000ULL) ? (e & 0x7FFFFFFFFFFFFFFFULL) : ~e;
    return __longlong_as_double((long long)u);
}

__global__ void initK(unsigned* minenc, unsigned* maxenc, unsigned long long* rmaxenc,
                      unsigned* rowact, unsigned* colBits) {
    int t = threadIdx.x;
    if (t < NCH) { minenc[t] = 0xFFFFFFFFu; maxenc[t] = 0u; rmaxenc[t] = 0ULL; }
    for (int i = t; i < NCH*16; i += 1024) { rowact[i] = 0u; colBits[i] = 0u; }
}

// weights: gw[o*288 + k] = g[k] for k in [0, 2r], zero elsewhere (k < 288)
__global__ void gaussK(float* gw) {
    int o = blockIdx.x;
    const int rr[6] = {4, 8, 17, 34, 67, 134};
    int r = rr[o];
    float sigma = 1.4f * (float)(1 << o);
    int t = threadIdx.x;   // 512
    int n = 2*r + 1;
    float wv = 0.f;
    if (t < n) { float ft = (float)(t - r) / sigma; wv = expf(-0.5f * ft * ft); }
    __shared__ float red[512];
    red[t] = wv; __syncthreads();
    for (int s = 256; s > 0; s >>= 1) { if (t < s) red[t] += red[t + s]; __syncthreads(); }
    float sum = red[0];
    float* g = gw + o*288;
    if (t < 288) g[t] = (t < n) ? wv / sum : 0.f;
}

__global__ void minmaxK(const float4* __restrict__ x4, unsigned* minenc, unsigned* maxenc) {
    int ch = blockIdx.y, chunk = blockIdx.x, t = threadIdx.x;
    size_t base = (size_t)ch*(NPX/4) + (size_t)chunk*8192;
    float mn = 3.4e38f, mx = -3.4e38f;
    for (int i = t; i < 8192; i += 256) {
        float4 v = x4[base + i];
        mn = fminf(mn, fminf(fminf(v.x, v.y), fminf(v.z, v.w)));
        mx = fmaxf(mx, fmaxf(fmaxf(v.x, v.y), fmaxf(v.z, v.w)));
    }
    for (int o = 32; o; o >>= 1) { mn = fminf(mn, __shfl_down(mn, o)); mx = fmaxf(mx, __shfl_down(mx, o)); }
    __shared__ float smn[4], smx[4];
    if ((t & 63) == 0) { smn[t >> 6] = mn; smx[t >> 6] = mx; }
    __syncthreads();
    if (t == 0) {
        for (int i = 1; i < 4; i++) { mn = fminf(mn, smn[i]); mx = fmaxf(mx, smx[i]); }
        atomicMin(&minenc[ch], encf(mn));
        atomicMax(&maxenc[ch], encf(mx));
    }
}

__global__ void scaleK(const unsigned* minenc, const unsigned* maxenc, double* gsd) {
    int t = threadIdx.x;
    if (t >= NCH) return;
    double mn = (double)decf(minenc[t]), mx = (double)decf(maxenc[t]);
    gsd[t] = 255.0 / (mx - mn + 1e-12);
}

// Harris R (fp64 direct) + Laplacian base. 32x32 tile/block, 5.2KB LDS.
__global__ __launch_bounds__(256) void lapRK(const float* __restrict__ x, const double* __restrict__ gsd,
                      float* __restrict__ lap, double* __restrict__ Rb,
                      unsigned long long* __restrict__ rmaxenc) {
    __shared__ float in[36*36];
    int ch = blockIdx.z;
    int px0 = blockIdx.x * 32, py0 = blockIdx.y * 32;
    const float* s = x + (size_t)ch*NPX;
    int t = threadIdx.x;
    for (int i = t; i < 36*36; i += 256) {
        int yy = i / 36, xx = i - yy*36;
        in[i] = s[(size_t)refl(py0 - 2 + yy)*W + refl(px0 - 2 + xx)];
    }
    __syncthreads();
    double sd = gsd[ch], s2 = sd*sd;
    int tx = t & 31, ty0 = (t >> 5) * 4;
    int gx = px0 + tx;
    int cb = gx ? tx : 1;               // local col of window base
    double m = -1e308;
    #pragma unroll
    for (int q = 0; q < 4; q++) {
        int ly = ty0 + q;
        int gy = py0 + ly;
        int rb = gy ? ly : 1;           // local row of window base
        double w[4][4];
        #pragma unroll
        for (int j = 0; j < 4; j++) {
            const float* rp = &in[(rb + j)*36 + cb];
            w[j][0] = (double)rp[0]; w[j][1] = (double)rp[1];
            w[j][2] = (double)rp[2]; w[j][3] = (double)rp[3];
        }
        double cs1[4], cs2[4], rs[4][2];
        #pragma unroll
        for (int c2 = 0; c2 < 4; c2++) {
            cs1[c2] = w[0][c2] + 2.0*w[1][c2] + w[2][c2];
            cs2[c2] = w[1][c2] + 2.0*w[2][c2] + w[3][c2];
        }
        #pragma unroll
        for (int j = 0; j < 4; j++) {
            rs[j][0] = w[j][0] + 2.0*w[j][1] + w[j][2];
            rs[j][1] = w[j][1] + 2.0*w[j][2] + w[j][3];
        }
        double Sxx = 0, Syy = 0, Sxy = 0;
        {
            double ix, iy;
            ix = cs1[2]-cs1[0]; iy = rs[2][0]-rs[0][0]; Sxx += ix*ix; Syy += iy*iy; Sxy += ix*iy;
            ix = cs1[3]-cs1[1]; iy = rs[2][1]-rs[0][1]; Sxx += ix*ix; Syy += iy*iy; Sxy += ix*iy;
            ix = cs2[2]-cs2[0]; iy = rs[3][0]-rs[1][0]; Sxx += ix*ix; Syy += iy*iy; Sxy += ix*iy;
            ix = cs2[3]-cs2[1]; iy = rs[3][1]-rs[1][1]; Sxx += ix*ix; Syy += iy*iy; Sxy += ix*iy;
        }
        Sxx *= s2; Syy *= s2; Sxy *= s2;
        double tr = Sxx + Syy;
        double R = Sxx*Syy - Sxy*Sxy - 0.04*tr*tr;
        Rb[(size_t)ch*NPX + (size_t)gy*W + gx] = R;
        const float* c = &in[(ly+2)*36 + (tx+2)];
        double l = 2.0*((double)c[-37] + (double)c[-35] + (double)c[35] + (double)c[37]) - 8.0*(double)c[0];
        lap[(size_t)ch*NPX + (size_t)gy*W + gx] = (float)(sd * l);
        m = fmax(m, R);
    }
    for (int o = 32; o; o >>= 1) m = fmax(m, __shfl_down(m, o));
    __shared__ double sred[4];
    if ((t & 63) == 0) sred[t >> 6] = m;
    __syncthreads();
    if (t == 0) {
        for (int i = 1; i < 4; i++) m = fmax(m, sred[i]);
        atomicMax(&rmaxenc[ch], enc64(m));
    }
}

// fused threshold + 3x3 dilate; writes TRANSPOSED mask maskT[ch][x][y];
// also builds row-activity and column-activity bitmaps
__global__ __launch_bounds__(256) void maskTK(const double* __restrict__ Rb,
                                              const unsigned long long* __restrict__ rmaxenc,
                                              unsigned char* __restrict__ maskT,
                                              unsigned* __restrict__ rowact,
                                              unsigned* __restrict__ colBits) {
    __shared__ int bt[34*34];
    __shared__ unsigned char vt[32][33];
    __shared__ unsigned rw, cw;
    int ch = blockIdx.z;
    int px0 = blockIdx.x*32, py0 = blockIdx.y*32;
    double thr = 0.01 * dec64(rmaxenc[ch]);
    const double* R = Rb + (size_t)ch*NPX;
    int t = threadIdx.x;
    if (t == 0) { rw = 0u; cw = 0u; }
    for (int i = t; i < 34*34; i += 256) {
        int yy = i / 34, xx = i - yy*34;
        int gy = py0 - 1 + yy, gx = px0 - 1 + xx;
        int v = 0;
        if ((unsigned)gy < 512u && (unsigned)gx < 512u) v = (R[(size_t)gy*W + gx] > thr) ? 1 : 0;
        bt[i] = v;
    }
    __syncthreads();
    int tx = t & 31, ty0 = (t >> 5) * 4;
    int colv = 0;
    #pragma unroll
    for (int q = 0; q < 4; q++) {
        int ly = ty0 + q;
        int c = (ly+1)*34 + tx + 1;
        int v = bt[c-35] | bt[c-34] | bt[c-33] | bt[c-1] | bt[c] | bt[c+1] | bt[c+33] | bt[c+34] | bt[c+35];
        vt[tx][ly] = (unsigned char)v;
        colv |= v;
        unsigned long long bal = __ballot(v != 0);
        int lane = t & 63;
        if (lane == 0 && (unsigned)bal) atomicOr(&rw, 1u << (ty0 + q));
        if (lane == 32 && (unsigned)(bal >> 32)) atomicOr(&rw, 1u << (ty0 + q));
    }
    if (colv) atomicOr(&cw, 1u << tx);
    __syncthreads();
    // write transposed mask: thread t -> x row xl = t>>3, 4-byte y segment seg = t&7
    int xl = t >> 3, seg = t & 7;
    uchar4 u4 = make_uchar4(vt[xl][seg*4+0], vt[xl][seg*4+1], vt[xl][seg*4+2], vt[xl][seg*4+3]);
    *(uchar4*)(maskT + (size_t)ch*NPX + (size_t)(px0 + xl)*W + py0 + seg*4) = u4;
    if (t == 0) {
        if (rw) atomicOr(&rowact[ch*16 + (py0 >> 5)], rw);
        if (cw) atomicOr(&colBits[ch*16 + blockIdx.x], cw);
    }
}

// horizontal blur, SPARSE over active 16-col groups, TRANSPOSED output.
// 16 rows/block; lanes take active-group list entries xi, xi+16 (<=2 rounds).
// Group g covers cols [16g,16g+16); active iff its colBits halfword != 0
// (supersets colblurT's 8-col cbits gate, so all consumed Tt cols are computed).
// Ascending-tap chunk loop identical to dense version -> FP-identical values.
__global__ __launch_bounds__(256) void rowblurT(const float* __restrict__ src, float* __restrict__ Tt,
                                                const float* __restrict__ gwo, int r, int nc16,
                                                const unsigned* __restrict__ rowact,
                                                const unsigned* __restrict__ colBits) {
    int ch = blockIdx.y;
    int row0 = blockIdx.x * 16;
    int t = threadIdx.x;
    // early exit: no masked row in [row0-r, row0+15+r]
    {
        int lo = row0 - r; if (lo < 0) lo = 0;
        int hi = row0 + 15 + r; if (hi > 511) hi = 511;
        int w0 = lo >> 5, w1 = hi >> 5;
        int lane = t & 63;
        unsigned any = 0;
        if (lane <= w1 - w0) {
            int wi = w0 + lane;
            unsigned word = rowact[ch*16 + wi];
            int b0 = wi*32;
            int lo2 = lo > b0 ? lo - b0 : 0;
            int hi2 = hi < b0 + 31 ? hi - b0 : 31;
            unsigned mlo = ~0u << lo2;
            unsigned mhi = (hi2 == 31) ? ~0u : ((1u << (hi2 + 1)) - 1u);
            any = word & mlo & mhi;
        }
        if (!__any((int)(any != 0))) return;
    }
    extern __shared__ float sm[];   // 16*16*49 = 12544 floats (>= 512*17 = 8704)
    __shared__ float wls[288];
    __shared__ unsigned char gl[32];
    __shared__ int ngs;
    int lr = t >> 4, xi = t & 15;
    for (int i = t; i < 288; i += 256) wls[i] = gwo[i];
    // compact active 16-col groups (first wave)
    if (t < 64) {
        bool act = false;
        if (t < 32) {
            unsigned cw = colBits[ch*16 + (t >> 1)];
            act = ((cw >> ((t & 1)*16)) & 0xFFFFu) != 0u;
        }
        unsigned long long bal = __ballot(act);
        if (act) gl[__popcll(bal & ((1ull << t) - 1ull))] = (unsigned char)t;
        if (t == 0) ngs = (int)__popcll(bal);
    }
    const float* s = src + (size_t)ch*NPX + (size_t)(row0 + lr)*W;
    int n = W + 2*r;
    float* ESr = sm + lr*784;
    for (int j = xi; j < 784; j += 16)
        ESr[(j & 15)*49 + (j >> 4)] = (j < n) ? s[refl(j - r)] : 0.f;
    __syncthreads();
    int ng = ngs;
    if (ng == 0) return;   // uniform
    float aa[2][16];
    int g2[2] = {-1, -1};
    #pragma unroll
    for (int ri = 0; ri < 2; ri++) {
        int gi = xi + 16*ri;
        if (gi < ng) {
            int g = gl[gi];
            g2[ri] = g;
            float a[16];
            #pragma unroll
            for (int m = 0; m < 16; m++) a[m] = 0.f;
            for (int cc = 0; cc < nc16; ++cc) {
                float wv[16], f[31];
                #pragma unroll
                for (int i = 0; i < 16; i++) wv[i] = wls[16*cc + i];
                #pragma unroll
                for (int j = 0; j < 31; j++) f[j] = ESr[(j & 15)*49 + (g + cc + (j >> 4))];
                #pragma unroll
                for (int m = 0; m < 16; m++) {
                    #pragma unroll
                    for (int i = 0; i < 16; i++) a[m] = fmaf(wv[i], f[m + i], a[m]);
                }
            }
            #pragma unroll
            for (int m = 0; m < 16; m++) aa[ri][m] = a[m];
        }
    }
    __syncthreads();   // ES dead, reuse sm as ot[512][17]
    #pragma unroll
    for (int ri = 0; ri < 2; ri++) {
        if (g2[ri] >= 0) {
            int cb = 16*g2[ri];
            #pragma unroll
            for (int m = 0; m < 16; m++) sm[(cb + m)*17 + lr] = aa[ri][m];
        }
    }
    __syncthreads();
    float* dto = Tt + (size_t)ch*NPX + row0;
    int tot = 16*ng;
    for (int ci = t; ci < tot; ci += 256) {
        int col = 16*gl[ci >> 4] + (ci & 15);
        const float* o = sm + col*17;
        float4* d = (float4*)(dto + (size_t)col*W);
        d[0] = make_float4(o[0],  o[1],  o[2],  o[3]);
        d[1] = make_float4(o[4],  o[5],  o[6],  o[7]);
        d[2] = make_float4(o[8],  o[9],  o[10], o[11]);
        d[3] = make_float4(o[12], o[13], o[14], o[15]);
    }
}

// vertical blur done as HORIZONTAL blur on Tt: 8 x-rows/block, 16 y/thread,
// same chunked ascending-tap loop. Per-channel skip via colBits (8-col cbits);
// per-wave skip via maskT; accumulates into transposed outT[b][x][y].
template<int WRITE0>
__global__ __launch_bounds__(256, 4) void colblurT(const float* __restrict__ Tt,
                                                   const unsigned char* __restrict__ maskT,
                                                   float* __restrict__ outT,
                                                   const float* __restrict__ gwo,
                                                   int r, int nc16, float sigma,
                                                   const unsigned* __restrict__ colBits) {
    __shared__ float ES[8*16*49];
    __shared__ float wls[288];
    int b = blockIdx.y;
    int x0 = blockIdx.x * 8;
    int t = threadIdx.x;
    int lr = t >> 5, xi = t & 31;
    for (int i = t; i < 288; i += 256) wls[i] = gwo[i];
    float vm[16];
    #pragma unroll
    for (int m = 0; m < 16; m++) vm[m] = 0.f;
    int anyAct = 0;
    int n = W + 2*r;
    float* ESr = ES + lr*16*49;
    for (int c = 0; c < 3; ++c) {
        int ch = b*3 + c;
        unsigned cbits = (colBits[ch*16 + (x0 >> 5)] >> (x0 & 31)) & 0xFFu;
        if (!cbits) continue;          // uniform per block
        anyAct = 1;
        __syncthreads();               // protect ES from previous channel's readers
        const float* s = Tt + (size_t)ch*NPX + (size_t)(x0 + lr)*W;
        for (int j = xi; j < 784; j += 32)
            ESr[(j & 15)*49 + (j >> 4)] = (j < n) ? s[refl(j - r)] : 0.f;
        __syncthreads();
        const uchar4* mp = (const uchar4*)(maskT + (size_t)ch*NPX + (size_t)(x0 + lr)*W + 16*xi);
        uchar4 m0 = mp[0], m1 = mp[1], m2 = mp[2], m3 = mp[3];
        unsigned mk = 0;
        mk |=  (m0.x?1u:0u)|(m0.y?2u:0u)|(m0.z?4u:0u)|(m0.w?8u:0u);
        mk |= ((m1.x?1u:0u)|(m1.y?2u:0u)|(m1.z?4u:0u)|(m1.w?8u:0u)) << 4;
        mk |= ((m2.x?1u:0u)|(m2.y?2u:0u)|(m2.z?4u:0u)|(m2.w?8u:0u)) << 8;
        mk |= ((m3.x?1u:0u)|(m3.y?2u:0u)|(m3.z?4u:0u)|(m3.w?8u:0u)) << 12;
        if (__any((int)(mk != 0))) {
            float a[16];
            #pragma unroll
            for (int m = 0; m < 16; m++) a[m] = 0.f;
            for (int cc = 0; cc < nc16; ++cc) {
                float wv[16], f[31];
                #pragma unroll
                for (int i = 0; i < 16; i++) wv[i] = wls[16*cc + i];
                #pragma unroll
                for (int j = 0; j < 31; j++) f[j] = ESr[(j & 15)*49 + (xi + cc + (j >> 4))];
                #pragma unroll
                for (int m = 0; m < 16; m++) {
                    #pragma unroll
                    for (int i = 0; i < 16; i++) a[m] = fmaf(wv[i], f[m + i], a[m]);
                }
            }
            #pragma unroll
            for (int m = 0; m < 16; m++)
                if (mk & (1u << m)) vm[m] = fmaxf(vm[m], sigma * fabsf(a[m]));
        }
    }
    if (!WRITE0 && !anyAct) return;
    float* ob = outT + (size_t)b*NPX + (size_t)(x0 + lr)*W + 16*xi;
    #pragma unroll
    for (int q = 0; q < 4; q++) {
        float4 vv = make_float4(vm[4*q], vm[4*q+1], vm[4*q+2], vm[4*q+3]);
        if (!WRITE0) {
            float4 cur = ((const float4*)ob)[q];
            vv.x = fmaxf(vv.x, cur.x); vv.y = fmaxf(vv.y, cur.y);
            vv.z = fmaxf(vv.z, cur.z); vv.w = fmaxf(vv.w, cur.w);
        }
        ((float4*)ob)[q] = vv;
    }
}

// final transpose: out[b][y][x] = outT[b][x][y]
__global__ __launch_bounds__(256) void transposeK(const float* __restrict__ outT, float* __restrict__ out) {
    __shared__ float tl[32][33];
    int b = blockIdx.z;
    int x0 = blockIdx.x * 32, y0 = blockIdx.y * 32;
    int t = threadIdx.x;
    int col = t & 31, rr = t >> 5;
    const float* src = outT + (size_t)b*NPX;
    #pragma unroll
    for (int k = 0; k < 4; k++) {
        int xr = rr + 8*k;
        tl[xr][col] = src[(size_t)(x0 + xr)*W + y0 + col];
    }
    __syncthreads();
    float* d = out + (size_t)b*NPX;
    #pragma unroll
    for (int k = 0; k < 4; k++) {
        int yr = rr + 8*k;
        d[(size_t)(y0 + yr)*W + x0 + col] = tl[col][yr];
    }
}

extern "C" void kernel_launch(void* const* d_in, const int* in_sizes, int n_in,
                              void* d_out, int out_size, void* d_ws, size_t ws_size,
                              hipStream_t stream) {
    const float* x = (const float*)d_in[0];
    float* out = (float*)d_out;
    char* w = (char*)d_ws;
    unsigned* minenc           = (unsigned*)(w + 1024);
    unsigned* maxenc           = (unsigned*)(w + 1280);
    unsigned long long* rmaxenc= (unsigned long long*)(w + 1536);
    double*  gsd               = (double*)(w + 256);
    float*   gw                = (float*)(w + 2048);                 // 6*288 floats
    unsigned* rowact           = (unsigned*)(w + 9216);              // 48*16 words
    unsigned* colBits          = (unsigned*)(w + 12288);             // 48*16 words
    float*   lap               = (float*)(w + 16384);                // 50331648 B
    double*  Rb                = (double*)(w + 16384 + 50331648);    // 100663296 B (freed after maskTK)
    float*   Tt                = (float*)Rb;                         // 50331648 B  (in Rb)
    float*   outT              = (float*)(w + 16384 + 50331648 + 50331648); // 16777216 B (in Rb)
    unsigned char* maskT       = (unsigned char*)(w + 16384 + 50331648 + 100663296); // 12582912 B

    initK<<<1, 1024, 0, stream>>>(minenc, maxenc, rmaxenc, rowact, colBits);
    gaussK<<<6, 512, 0, stream>>>(gw);
    minmaxK<<<dim3(8, 48), 256, 0, stream>>>((const float4*)x, minenc, maxenc);
    scaleK<<<1, 64, 0, stream>>>(minenc, maxenc, gsd);
    lapRK<<<dim3(16, 16, 48), 256, 0, stream>>>(x, gsd, lap, Rb, rmaxenc);
    maskTK<<<dim3(16, 16, 48), 256, 0, stream>>>(Rb, rmaxenc, maskT, rowact, colBits);

    const int rr[6] = {4, 8, 17, 34, 67, 134};
    for (int o = 0; o < 6; ++o) {
        int r = rr[o];
        int nc16 = (2*r + 1 + 15) / 16;
        float sigma = 1.4f * (float)(1 << o);
        size_t lds = 16*16*49 * 4;   // 50176 B (>= 512*17*4)
        rowblurT<<<dim3(32, 48), 256, lds, stream>>>(lap, Tt, gw + o*288, r, nc16, rowact, colBits);
        if (o == 0)
            colblurT<1><<<dim3(64, 16), 256, 0, stream>>>(Tt, maskT, outT, gw + o*288, r, nc16, sigma, colBits);
        else
            colblurT<0><<<dim3(64, 16), 256, 0, stream>>>(Tt, maskT, outT, gw + o*288, r, nc16, sigma, colBits);
    }
    transposeK<<<dim3(16, 16, 16), 256, 0, stream>>>(outT, out);
}

// Round 10
// 812.929 us; speedup vs baseline: 24.8313x; 1.0695x over previous
//
#include <hip/hip_runtime.h>

#define W 512
#define NPX (512*512)
#define NCH 48
#define NBATCH 16

// reflect-101 index mapping into [0,511]; valid for i in [-511, 1022]
__device__ __forceinline__ int refl(int i) {
    int a = i < 0 ? -i : i;
    int b = 1022 - a;
    return a < b ? a : b;
}
__device__ __forceinline__ unsigned encf(float f) {
    unsigned u = __float_as_uint(f);
    return (u & 0x80000000u) ? ~u : (u | 0x80000000u);
}
__device__ __forceinline__ float decf(unsigned e) {
    unsigned u = (e & 0x80000000u) ? (e & 0x7FFFFFFFu) : ~e;
    return __uint_as_float(u);
}
__device__ __forceinline__ unsigned long long enc64(double d) {
    unsigned long long u = (unsigned long long)__double_as_longlong(d);
    return (u & 0x8000000000000000ULL) ? ~u : (u | 0x8000000000000000ULL);
}
__device__ __forceinline__ double dec64(unsigned long long e) {
    unsigned long long u = (e & 0x8000000000000000ULL) ? (e & 0x7FFFFFFFFFFFFFFFULL) : ~e;
    return __longlong_as_double((long long)u);
}

__global__ void initK(unsigned* minenc, unsigned* maxenc, unsigned long long* rmaxenc,
                      unsigned* rowact, unsigned* colBits) {
    int t = threadIdx.x;
    if (t < NCH) { minenc[t] = 0xFFFFFFFFu; maxenc[t] = 0u; rmaxenc[t] = 0ULL; }
    for (int i = t; i < NCH*16; i += 1024) { rowact[i] = 0u; colBits[i] = 0u; }
}

// weights: gw[o*288 + k] = g[k] for k in [0, 2r], zero elsewhere (k < 288)
__global__ void gaussK(float* gw) {
    int o = blockIdx.x;
    const int rr[6] = {4, 8, 17, 34, 67, 134};
    int r = rr[o];
    float sigma = 1.4f * (float)(1 << o);
    int t = threadIdx.x;   // 512
    int n = 2*r + 1;
    float wv = 0.f;
    if (t < n) { float ft = (float)(t - r) / sigma; wv = expf(-0.5f * ft * ft); }
    __shared__ float red[512];
    red[t] = wv; __syncthreads();
    for (int s = 256; s > 0; s >>= 1) { if (t < s) red[t] += red[t + s]; __syncthreads(); }
    float sum = red[0];
    float* g = gw + o*288;
    if (t < 288) g[t] = (t < n) ? wv / sum : 0.f;
}

__global__ void minmaxK(const float4* __restrict__ x4, unsigned* minenc, unsigned* maxenc) {
    int ch = blockIdx.y, chunk = blockIdx.x, t = threadIdx.x;
    size_t base = (size_t)ch*(NPX/4) + (size_t)chunk*8192;
    float mn = 3.4e38f, mx = -3.4e38f;
    for (int i = t; i < 8192; i += 256) {
        float4 v = x4[base + i];
        mn = fminf(mn, fminf(fminf(v.x, v.y), fminf(v.z, v.w)));
        mx = fmaxf(mx, fmaxf(fmaxf(v.x, v.y), fmaxf(v.z, v.w)));
    }
    for (int o = 32; o; o >>= 1) { mn = fminf(mn, __shfl_down(mn, o)); mx = fmaxf(mx, __shfl_down(mx, o)); }
    __shared__ float smn[4], smx[4];
    if ((t & 63) == 0) { smn[t >> 6] = mn; smx[t >> 6] = mx; }
    __syncthreads();
    if (t == 0) {
        for (int i = 1; i < 4; i++) { mn = fminf(mn, smn[i]); mx = fmaxf(mx, smx[i]); }
        atomicMin(&minenc[ch], encf(mn));
        atomicMax(&maxenc[ch], encf(mx));
    }
}

__global__ void scaleK(const unsigned* minenc, const unsigned* maxenc, double* gsd) {
    int t = threadIdx.x;
    if (t >= NCH) return;
    double mn = (double)decf(minenc[t]), mx = (double)decf(maxenc[t]);
    gsd[t] = 255.0 / (mx - mn + 1e-12);
}

// Harris R (fp64 direct) + Laplacian base. 32x32 tile/block, 5.2KB LDS.
__global__ __launch_bounds__(256) void lapRK(const float* __restrict__ x, const double* __restrict__ gsd,
                      float* __restrict__ lap, double* __restrict__ Rb,
                      unsigned long long* __restrict__ rmaxenc) {
    __shared__ float in[36*36];
    int ch = blockIdx.z;
    int px0 = blockIdx.x * 32, py0 = blockIdx.y * 32;
    const float* s = x + (size_t)ch*NPX;
    int t = threadIdx.x;
    for (int i = t; i < 36*36; i += 256) {
        int yy = i / 36, xx = i - yy*36;
        in[i] = s[(size_t)refl(py0 - 2 + yy)*W + refl(px0 - 2 + xx)];
    }
    __syncthreads();
    double sd = gsd[ch], s2 = sd*sd;
    int tx = t & 31, ty0 = (t >> 5) * 4;
    int gx = px0 + tx;
    int cb = gx ? tx : 1;               // local col of window base
    double m = -1e308;
    #pragma unroll
    for (int q = 0; q < 4; q++) {
        int ly = ty0 + q;
        int gy = py0 + ly;
        int rb = gy ? ly : 1;           // local row of window base
        double w[4][4];
        #pragma unroll
        for (int j = 0; j < 4; j++) {
            const float* rp = &in[(rb + j)*36 + cb];
            w[j][0] = (double)rp[0]; w[j][1] = (double)rp[1];
            w[j][2] = (double)rp[2]; w[j][3] = (double)rp[3];
        }
        double cs1[4], cs2[4], rs[4][2];
        #pragma unroll
        for (int c2 = 0; c2 < 4; c2++) {
            cs1[c2] = w[0][c2] + 2.0*w[1][c2] + w[2][c2];
            cs2[c2] = w[1][c2] + 2.0*w[2][c2] + w[3][c2];
        }
        #pragma unroll
        for (int j = 0; j < 4; j++) {
            rs[j][0] = w[j][0] + 2.0*w[j][1] + w[j][2];
            rs[j][1] = w[j][1] + 2.0*w[j][2] + w[j][3];
        }
        double Sxx = 0, Syy = 0, Sxy = 0;
        {
            double ix, iy;
            ix = cs1[2]-cs1[0]; iy = rs[2][0]-rs[0][0]; Sxx += ix*ix; Syy += iy*iy; Sxy += ix*iy;
            ix = cs1[3]-cs1[1]; iy = rs[2][1]-rs[0][1]; Sxx += ix*ix; Syy += iy*iy; Sxy += ix*iy;
            ix = cs2[2]-cs2[0]; iy = rs[3][0]-rs[1][0]; Sxx += ix*ix; Syy += iy*iy; Sxy += ix*iy;
            ix = cs2[3]-cs2[1]; iy = rs[3][1]-rs[1][1]; Sxx += ix*ix; Syy += iy*iy; Sxy += ix*iy;
        }
        Sxx *= s2; Syy *= s2; Sxy *= s2;
        double tr = Sxx + Syy;
        double R = Sxx*Syy - Sxy*Sxy - 0.04*tr*tr;
        Rb[(size_t)ch*NPX + (size_t)gy*W + gx] = R;
        const float* c = &in[(ly+2)*36 + (tx+2)];
        double l = 2.0*((double)c[-37] + (double)c[-35] + (double)c[35] + (double)c[37]) - 8.0*(double)c[0];
        lap[(size_t)ch*NPX + (size_t)gy*W + gx] = (float)(sd * l);
        m = fmax(m, R);
    }
    for (int o = 32; o; o >>= 1) m = fmax(m, __shfl_down(m, o));
    __shared__ double sred[4];
    if ((t & 63) == 0) sred[t >> 6] = m;
    __syncthreads();
    if (t == 0) {
        for (int i = 1; i < 4; i++) m = fmax(m, sred[i]);
        atomicMax(&rmaxenc[ch], enc64(m));
    }
}

// fused threshold + 3x3 dilate; writes TRANSPOSED mask maskT[ch][x][y];
// also builds row-activity and column-activity bitmaps
__global__ __launch_bounds__(256) void maskTK(const double* __restrict__ Rb,
                                              const unsigned long long* __restrict__ rmaxenc,
                                              unsigned char* __restrict__ maskT,
                                              unsigned* __restrict__ rowact,
                                              unsigned* __restrict__ colBits) {
    __shared__ int bt[34*34];
    __shared__ unsigned char vt[32][33];
    __shared__ unsigned rw, cw;
    int ch = blockIdx.z;
    int px0 = blockIdx.x*32, py0 = blockIdx.y*32;
    double thr = 0.01 * dec64(rmaxenc[ch]);
    const double* R = Rb + (size_t)ch*NPX;
    int t = threadIdx.x;
    if (t == 0) { rw = 0u; cw = 0u; }
    for (int i = t; i < 34*34; i += 256) {
        int yy = i / 34, xx = i - yy*34;
        int gy = py0 - 1 + yy, gx = px0 - 1 + xx;
        int v = 0;
        if ((unsigned)gy < 512u && (unsigned)gx < 512u) v = (R[(size_t)gy*W + gx] > thr) ? 1 : 0;
        bt[i] = v;
    }
    __syncthreads();
    int tx = t & 31, ty0 = (t >> 5) * 4;
    int colv = 0;
    #pragma unroll
    for (int q = 0; q < 4; q++) {
        int ly = ty0 + q;
        int c = (ly+1)*34 + tx + 1;
        int v = bt[c-35] | bt[c-34] | bt[c-33] | bt[c-1] | bt[c] | bt[c+1] | bt[c+33] | bt[c+34] | bt[c+35];
        vt[tx][ly] = (unsigned char)v;
        colv |= v;
        unsigned long long bal = __ballot(v != 0);
        int lane = t & 63;
        if (lane == 0 && (unsigned)bal) atomicOr(&rw, 1u << (ty0 + q));
        if (lane == 32 && (unsigned)(bal >> 32)) atomicOr(&rw, 1u << (ty0 + q));
    }
    if (colv) atomicOr(&cw, 1u << tx);
    __syncthreads();
    int xl = t >> 3, seg = t & 7;
    uchar4 u4 = make_uchar4(vt[xl][seg*4+0], vt[xl][seg*4+1], vt[xl][seg*4+2], vt[xl][seg*4+3]);
    *(uchar4*)(maskT + (size_t)ch*NPX + (size_t)(px0 + xl)*W + py0 + seg*4) = u4;
    if (t == 0) {
        if (rw) atomicOr(&rowact[ch*16 + (py0 >> 5)], rw);
        if (cw) atomicOr(&colBits[ch*16 + blockIdx.x], cw);
    }
}

// horizontal blur, TRANSPOSED output. 512 thr = 8 rows x 64 lanes; lane owns
// cols 8*xi..8*xi+7; 8-tap chunks; SoA-8 LDS (phase = e&7, slot = e>>3) so
// lane reads are stride-1 (conflict-free) and phases are compile-time.
// Tap order ascending -> FP-identical to prior rounds. rowact early-exit kept.
__global__ __launch_bounds__(512, 8) void rowblurK2(const float* __restrict__ src, float* __restrict__ Tt,
                                                    const float* __restrict__ gwo, int r, int nc8,
                                                    const unsigned* __restrict__ rowact) {
    int ch = blockIdx.y;
    int row0 = blockIdx.x * 8;
    int t = threadIdx.x;
    // early exit: no masked row in [row0-r, row0+7+r]
    {
        int lo = row0 - r; if (lo < 0) lo = 0;
        int hi = row0 + 7 + r; if (hi > 511) hi = 511;
        int w0 = lo >> 5, w1 = hi >> 5;
        int lane = t & 63;
        unsigned any = 0;
        if (lane <= w1 - w0) {
            int wi = w0 + lane;
            unsigned word = rowact[ch*16 + wi];
            int b0 = wi*32;
            int lo2 = lo > b0 ? lo - b0 : 0;
            int hi2 = hi < b0 + 31 ? hi - b0 : 31;
            unsigned mlo = ~0u << lo2;
            unsigned mhi = (hi2 == 31) ? ~0u : ((1u << (hi2 + 1)) - 1u);
            any = word & mlo & mhi;
        }
        if (!__any((int)(any != 0))) return;
    }
    __shared__ float ES[8*784];    // SoA-8 per row; reused as restage buffer
    __shared__ float wls[288];
    int lr = t >> 6, xi = t & 63;
    for (int i = t; i < 288; i += 512) wls[i] = gwo[i];
    const float* s = src + (size_t)ch*NPX + (size_t)(row0 + lr)*W;
    int n = W + 2*r;
    float* ESr = ES + lr*784;
    for (int j = xi; j < 784; j += 64)
        ESr[(j & 7)*98 + (j >> 3)] = (j < n) ? s[refl(j - r)] : 0.f;
    __syncthreads();
    float a[8];
    #pragma unroll
    for (int m = 0; m < 8; m++) a[m] = 0.f;
    for (int cc = 0; cc < nc8; ++cc) {
        float wv[8], f[15];
        #pragma unroll
        for (int i = 0; i < 8; i++) wv[i] = wls[8*cc + i];
        #pragma unroll
        for (int j = 0; j < 15; j++) f[j] = ESr[(j & 7)*98 + (xi + cc + (j >> 3))];
        #pragma unroll
        for (int m = 0; m < 8; m++) {
            #pragma unroll
            for (int i = 0; i < 8; i++) a[m] = fmaf(wv[i], f[m + i], a[m]);
        }
    }
    __syncthreads();   // ES dead; reuse as restage ot[512][9]
    #pragma unroll
    for (int m = 0; m < 8; m++) ES[(8*xi + m)*9 + lr] = a[m];
    __syncthreads();
    // write-out: thread t -> col t, 8 consecutive y (32B)
    {
        const float* o = ES + t*9;
        float4* d = (float4*)(Tt + (size_t)ch*NPX + (size_t)t*W + row0);
        d[0] = make_float4(o[0], o[1], o[2], o[3]);
        d[1] = make_float4(o[4], o[5], o[6], o[7]);
    }
}

// vertical blur as horizontal on Tt. 512 thr = 8 x-rows x 64 lanes; lane owns
// y = 8*xi..8*xi+7; 8-tap chunks; SoA-8 LDS. Per-channel skip via colBits;
// per-lane mask gating; accumulates octave/channel max into transposed outT.
template<int WRITE0>
__global__ __launch_bounds__(512, 8) void colblurK2(const float* __restrict__ Tt,
                                                    const unsigned char* __restrict__ maskT,
                                                    float* __restrict__ outT,
                                                    const float* __restrict__ gwo,
                                                    int r, int nc8, float sigma,
                                                    const unsigned* __restrict__ colBits) {
    __shared__ float ES[8*784];
    __shared__ float wls[288];
    int b = blockIdx.y;
    int x0 = blockIdx.x * 8;
    int t = threadIdx.x;
    int lr = t >> 6, xi = t & 63;
    for (int i = t; i < 288; i += 512) wls[i] = gwo[i];
    float vm[8];
    #pragma unroll
    for (int m = 0; m < 8; m++) vm[m] = 0.f;
    int anyAct = 0;
    int n = W + 2*r;
    float* ESr = ES + lr*784;
    for (int c = 0; c < 3; ++c) {
        int ch = b*3 + c;
        unsigned cbits = (colBits[ch*16 + (x0 >> 5)] >> (x0 & 31)) & 0xFFu;
        if (!cbits) continue;          // uniform per block
        anyAct = 1;
        __syncthreads();               // protect ES from previous channel's readers
        const float* s = Tt + (size_t)ch*NPX + (size_t)(x0 + lr)*W;
        for (int j = xi; j < 784; j += 64)
            ESr[(j & 7)*98 + (j >> 3)] = (j < n) ? s[refl(j - r)] : 0.f;
        __syncthreads();
        const uchar4* mp = (const uchar4*)(maskT + (size_t)ch*NPX + (size_t)(x0 + lr)*W + 8*xi);
        uchar4 m0 = mp[0], m1 = mp[1];
        unsigned mk = 0;
        mk |=  (m0.x?1u:0u)|(m0.y?2u:0u)|(m0.z?4u:0u)|(m0.w?8u:0u);
        mk |= ((m1.x?1u:0u)|(m1.y?2u:0u)|(m1.z?4u:0u)|(m1.w?8u:0u)) << 4;
        if (__any((int)(mk != 0))) {
            float a[8];
            #pragma unroll
            for (int m = 0; m < 8; m++) a[m] = 0.f;
            for (int cc = 0; cc < nc8; ++cc) {
                float wv[8], f[15];
                #pragma unroll
                for (int i = 0; i < 8; i++) wv[i] = wls[8*cc + i];
                #pragma unroll
                for (int j = 0; j < 15; j++) f[j] = ESr[(j & 7)*98 + (xi + cc + (j >> 3))];
                #pragma unroll
                for (int m = 0; m < 8; m++) {
                    #pragma unroll
                    for (int i = 0; i < 8; i++) a[m] = fmaf(wv[i], f[m + i], a[m]);
                }
            }
            #pragma unroll
            for (int m = 0; m < 8; m++)
                if (mk & (1u << m)) vm[m] = fmaxf(vm[m], sigma * fabsf(a[m]));
        }
    }
    if (!WRITE0 && !anyAct) return;
    float* ob = outT + (size_t)b*NPX + (size_t)(x0 + lr)*W + 8*xi;
    #pragma unroll
    for (int q = 0; q < 2; q++) {
        float4 vv = make_float4(vm[4*q], vm[4*q+1], vm[4*q+2], vm[4*q+3]);
        if (!WRITE0) {
            float4 cur = ((const float4*)ob)[q];
            vv.x = fmaxf(vv.x, cur.x); vv.y = fmaxf(vv.y, cur.y);
            vv.z = fmaxf(vv.z, cur.z); vv.w = fmaxf(vv.w, cur.w);
        }
        ((float4*)ob)[q] = vv;
    }
}

// final transpose: out[b][y][x] = outT[b][x][y]
__global__ __launch_bounds__(256) void transposeK(const float* __restrict__ outT, float* __restrict__ out) {
    __shared__ float tl[32][33];
    int b = blockIdx.z;
    int x0 = blockIdx.x * 32, y0 = blockIdx.y * 32;
    int t = threadIdx.x;
    int col = t & 31, rr = t >> 5;
    const float* src = outT + (size_t)b*NPX;
    #pragma unroll
    for (int k = 0; k < 4; k++) {
        int xr = rr + 8*k;
        tl[xr][col] = src[(size_t)(x0 + xr)*W + y0 + col];
    }
    __syncthreads();
    float* d = out + (size_t)b*NPX;
    #pragma unroll
    for (int k = 0; k < 4; k++) {
        int yr = rr + 8*k;
        d[(size_t)(y0 + yr)*W + x0 + col] = tl[col][yr];
    }
}

extern "C" void kernel_launch(void* const* d_in, const int* in_sizes, int n_in,
                              void* d_out, int out_size, void* d_ws, size_t ws_size,
                              hipStream_t stream) {
    const float* x = (const float*)d_in[0];
    float* out = (float*)d_out;
    char* w = (char*)d_ws;
    unsigned* minenc           = (unsigned*)(w + 1024);
    unsigned* maxenc           = (unsigned*)(w + 1280);
    unsigned long long* rmaxenc= (unsigned long long*)(w + 1536);
    double*  gsd               = (double*)(w + 256);
    float*   gw                = (float*)(w + 2048);                 // 6*288 floats
    unsigned* rowact           = (unsigned*)(w + 9216);              // 48*16 words
    unsigned* colBits          = (unsigned*)(w + 12288);             // 48*16 words
    float*   lap               = (float*)(w + 16384);                // 50331648 B
    char*    rb                = w + 16384 + 50331648;               // 100663296 B region
    double*  Rb                = (double*)rb;                        // fp64 R (consumed by maskTK)
    float*   Tt                = (float*)rb;                         // row-blur transposed (reuses Rb)
    float*   outT              = (float*)(rb + 50331648);            // 16777216 B
    unsigned char* maskT       = (unsigned char*)(w + 16384 + 50331648 + 100663296); // 12582912 B

    initK<<<1, 1024, 0, stream>>>(minenc, maxenc, rmaxenc, rowact, colBits);
    gaussK<<<6, 512, 0, stream>>>(gw);
    minmaxK<<<dim3(8, 48), 256, 0, stream>>>((const float4*)x, minenc, maxenc);
    scaleK<<<1, 64, 0, stream>>>(minenc, maxenc, gsd);
    lapRK<<<dim3(16, 16, 48), 256, 0, stream>>>(x, gsd, lap, Rb, rmaxenc);
    maskTK<<<dim3(16, 16, 48), 256, 0, stream>>>(Rb, rmaxenc, maskT, rowact, colBits);

    const int rr[6] = {4, 8, 17, 34, 67, 134};
    for (int o = 0; o < 6; ++o) {
        int r = rr[o];
        int nc8 = (2*r + 1 + 7) / 8;
        float sigma = 1.4f * (float)(1 << o);
        rowblurK2<<<dim3(64, 48), 512, 0, stream>>>(lap, Tt, gw + o*288, r, nc8, rowact);
        if (o == 0)
            colblurK2<1><<<dim3(64, 16), 512, 0, stream>>>(Tt, maskT, outT, gw + o*288, r, nc8, sigma, colBits);
        else
            colblurK2<0><<<dim3(64, 16), 512, 0, stream>>>(Tt, maskT, outT, gw + o*288, r, nc8, sigma, colBits);
    }
    transposeK<<<dim3(16, 16, 16), 256, 0, stream>>>(outT, out);
}